// Round 1
// baseline (556.383 us; speedup 1.0000x reference)
//
#include <hip/hip_runtime.h>

#define NN 100000   // nodes
#define NE 1600000  // edges
#define NG 100      // graphs
#define NPG 1000    // nodes per graph
#define CE 16       // edge channels
#define HH 64       // hidden
#define CAP 64      // max in-degree capacity (Poisson(16) tail ~3e-15 at 64)
#define BN_SCALE 0.99999500003749959f  // 1/sqrt(1+1e-5)

// ---------------- CSR fill (histogram + slot assignment via atomics) ----------------
__global__ void k_fill(const int* __restrict__ ei, int* __restrict__ cnt,
                       int* __restrict__ col_src, int* __restrict__ col_eid) {
  int e = blockIdx.x * blockDim.x + threadIdx.x;
  if (e >= NE) return;
  int s = ei[e];        // edge_index[0][e] = src
  int d = ei[NE + e];   // edge_index[1][e] = dst
  int pos = atomicAdd(&cnt[d], 1);
  if (pos < CAP) {
    col_src[d * CAP + pos] = s;
    col_eid[d * CAP + pos] = e;
  }
}

// ---------------- S_e[n][c] = 1 + sum_{e: dst=n} edge_attr[e][c] ----------------
__global__ void k_se(const int* __restrict__ cnt, const int* __restrict__ col_eid,
                     const float* __restrict__ ea, float* __restrict__ Se) {
  int t = blockIdx.x * blockDim.x + threadIdx.x;
  int n = t >> 4;
  if (n >= NN) return;
  int c = t & 15;
  int deg = min(cnt[n], CAP);
  const int* cep = col_eid + (size_t)n * CAP;
  float acc = 1.0f;  // self-loop ea = ones
  for (int k = 0; k < deg; ++k) {
    int e = cep[k];
    acc += ea[(size_t)e * CE + c];
  }
  Se[(size_t)n * CE + c] = acc;
}

// ---------------- per-layer node GEMM ----------------
// y[n][h] = x[n] @ W_j[:,h]                         (message term, gathered later)
// z[n][h] = deg[n]*(x[n] @ W_i[:,h] + b[h]) + S_e[n] @ W_e[:,h]   (local term)
// W layout per layer: rows 0..63 = W_i (x_dst/self), 64..127 = W_j (x_src), 128..143 = W_e
__global__ __launch_bounds__(256) void k_gemm(
    const float* __restrict__ x, const float* __restrict__ W,
    const float* __restrict__ b, const int* __restrict__ cnt,
    const float* __restrict__ Se, float* __restrict__ y, float* __restrict__ z) {
  __shared__ float Wl[144 * 64];
  __shared__ float bl[64];
  for (int i = threadIdx.x; i < 144 * 64; i += blockDim.x) Wl[i] = W[i];
  if (threadIdx.x < 64) bl[threadIdx.x] = b[threadIdx.x];
  __syncthreads();
  int lane = threadIdx.x & 63;
  // cache W columns in registers (static indexing only -> stays in VGPRs)
  float wi[64], wj[64], we[16];
#pragma unroll
  for (int k = 0; k < 64; ++k) wi[k] = Wl[k * 64 + lane];
#pragma unroll
  for (int k = 0; k < 64; ++k) wj[k] = Wl[(64 + k) * 64 + lane];
#pragma unroll
  for (int k = 0; k < 16; ++k) we[k] = Wl[(128 + k) * 64 + lane];
  float bv = bl[lane];
  int wid = blockIdx.x * (blockDim.x >> 6) + (threadIdx.x >> 6);
  int nw = gridDim.x * (blockDim.x >> 6);
  for (int n0 = wid; n0 < NN; n0 += nw) {
    int n = __builtin_amdgcn_readfirstlane(n0);  // force wave-uniform -> s_load x row
    const float* xr = x + (size_t)n * HH;
    const float* sr = Se + (size_t)n * CE;
    float a0 = 0.f, a1 = 0.f, a2 = 0.f, a3 = 0.f;  // y accumulators
    float c0 = 0.f, c1 = 0.f, c2 = 0.f, c3 = 0.f;  // z accumulators
#pragma unroll
    for (int k = 0; k < 64; k += 4) {
      float x0 = xr[k], x1 = xr[k + 1], x2 = xr[k + 2], x3 = xr[k + 3];
      a0 = fmaf(x0, wj[k], a0);
      a1 = fmaf(x1, wj[k + 1], a1);
      a2 = fmaf(x2, wj[k + 2], a2);
      a3 = fmaf(x3, wj[k + 3], a3);
      c0 = fmaf(x0, wi[k], c0);
      c1 = fmaf(x1, wi[k + 1], c1);
      c2 = fmaf(x2, wi[k + 2], c2);
      c3 = fmaf(x3, wi[k + 3], c3);
    }
    float s0 = 0.f, s1 = 0.f;
#pragma unroll
    for (int k = 0; k < 16; k += 2) {
      s0 = fmaf(sr[k], we[k], s0);
      s1 = fmaf(sr[k + 1], we[k + 1], s1);
    }
    float deg = (float)(min(cnt[n], CAP) + 1);
    y[(size_t)n * HH + lane] = (a0 + a1) + (a2 + a3);
    z[(size_t)n * HH + lane] = deg * (((c0 + c1) + (c2 + c3)) + bv) + (s0 + s1);
  }
}

// ---------------- per-layer gather + activation/BN ----------------
// x_new[n] = relu(bn(relu(z[n] + y[n] + sum_{e:dst=n} y[src_e])))   (in-place into z)
__global__ __launch_bounds__(256) void k_gather(
    const float* __restrict__ y, float* __restrict__ zx,
    const int* __restrict__ cnt, const int* __restrict__ col_src,
    const float* __restrict__ gamma, const float* __restrict__ beta,
    float* __restrict__ emb) {
  int lane = threadIdx.x & 63;
  int n0 = blockIdx.x * (blockDim.x >> 6) + (threadIdx.x >> 6);
  if (n0 >= NN) return;
  int n = __builtin_amdgcn_readfirstlane(n0);
  int deg = min(cnt[n], CAP);
  const int* cl = col_src + (size_t)n * CAP;   // wave-uniform -> scalar loads
  float acc = zx[(size_t)n * HH + lane] + y[(size_t)n * HH + lane];  // local + self-loop
  int k = 0;
  for (; k + 4 <= deg; k += 4) {
    int s0 = cl[k], s1 = cl[k + 1], s2 = cl[k + 2], s3 = cl[k + 3];
    float v0 = y[(size_t)s0 * HH + lane];
    float v1 = y[(size_t)s1 * HH + lane];
    float v2 = y[(size_t)s2 * HH + lane];
    float v3 = y[(size_t)s3 * HH + lane];
    acc += v0; acc += v1; acc += v2; acc += v3;
  }
  for (; k < deg; ++k) acc += y[(size_t)cl[k] * HH + lane];
  acc = fmaxf(acc, 0.f);                         // relu inside MP layer
  acc = gamma[lane] * acc * BN_SCALE + beta[lane];  // eval BN
  acc = fmaxf(acc, 0.f);                         // relu after BN
  zx[(size_t)n * HH + lane] = acc;
  if (n % NPG == 0) emb[(n / NPG) * HH + lane] = acc;  // spec_idx = g*NPG
}

// ---------------- readout: pool + MLP ----------------
__global__ __launch_bounds__(256) void k_final(
    const float* __restrict__ xf, const float* __restrict__ emb,
    const float* __restrict__ nbr, const float* __restrict__ fc1w,
    const float* __restrict__ fc1b, const float* __restrict__ fc2w,
    const float* __restrict__ fc2b, float* __restrict__ out) {
  __shared__ float feats[320];
  __shared__ float pool4[4][64];
  __shared__ float r1[256];
  int g = blockIdx.x;
  int t = threadIdx.x;
  int lane = t & 63, w = t >> 6;
  if (t >= 64) {  // fill embs: feats[64..255]
    int j = t - 64;
    feats[64 + j] = emb[((size_t)(j >> 6) * NG + g) * HH + (j & 63)];
  }
  if (t < 64) feats[256 + t] = nbr[(size_t)g * HH + t];  // neighbor
  float acc = 0.f;
  for (int i = w; i < NPG; i += 4) acc += xf[(size_t)(g * NPG + i) * HH + lane];
  pool4[w][lane] = acc;
  __syncthreads();
  if (t < 64) feats[t] = pool4[0][t] + pool4[1][t] + pool4[2][t] + pool4[3][t];
  __syncthreads();
  float a = fc1b[t];
  for (int k = 0; k < 320; ++k) a = fmaf(feats[k], fc1w[k * 256 + t], a);
  r1[t] = fmaxf(a, 0.f);
  __syncthreads();
  if (t < 4) {
    float o = fc2b[t];
    for (int k = 0; k < 256; ++k) o = fmaf(r1[k], fc2w[k * 4 + t], o);
    out[g * 4 + t] = o;
  }
}

extern "C" void kernel_launch(void* const* d_in, const int* in_sizes, int n_in,
                              void* d_out, int out_size, void* d_ws, size_t ws_size,
                              hipStream_t stream) {
  const float* x     = (const float*)d_in[0];
  const float* eattr = (const float*)d_in[1];
  const float* nbr   = (const float*)d_in[2];
  const float* W     = (const float*)d_in[3];
  const float* b     = (const float*)d_in[4];
  const float* gamma = (const float*)d_in[5];
  const float* beta  = (const float*)d_in[6];
  const float* fc1w  = (const float*)d_in[7];
  const float* fc1b  = (const float*)d_in[8];
  const float* fc2w  = (const float*)d_in[9];
  const float* fc2b  = (const float*)d_in[10];
  const int*   ei    = (const int*)d_in[11];
  float* out = (float*)d_out;
  (void)in_sizes; (void)n_in; (void)out_size; (void)ws_size;

  char* p = (char*)d_ws;
  size_t off = 0;
  auto alloc = [&](size_t bytes) {
    char* q = p + off;
    off += (bytes + 255) & ~(size_t)255;
    return q;
  };
  int*   cnt     = (int*)alloc((size_t)NN * 4);
  int*   col_src = (int*)alloc((size_t)NN * CAP * 4);
  int*   col_eid = (int*)alloc((size_t)NN * CAP * 4);
  float* Se      = (float*)alloc((size_t)NN * CE * 4);
  float* ybuf    = (float*)alloc((size_t)NN * HH * 4);
  float* zA      = (float*)alloc((size_t)NN * HH * 4);
  float* zB      = (float*)alloc((size_t)NN * HH * 4);
  float* emb     = (float*)alloc((size_t)3 * NG * HH * 4);

  hipMemsetAsync(cnt, 0, (size_t)NN * 4, stream);
  k_fill<<<(NE + 255) / 256, 256, 0, stream>>>(ei, cnt, col_src, col_eid);
  k_se<<<(NN * 16 + 255) / 256, 256, 0, stream>>>(cnt, col_eid, eattr, Se);

  const int GB = 768;     // gemm: 3072 waves, grid-stride over nodes
  const int GTB = 25000;  // gather: 4 waves/block, wave-per-node

  // layer 0: x -> zA
  k_gemm<<<GB, 256, 0, stream>>>(x, W, b, cnt, Se, ybuf, zA);
  k_gather<<<GTB, 256, 0, stream>>>(ybuf, zA, cnt, col_src, gamma, beta, emb);
  // layer 1: zA -> zB
  k_gemm<<<GB, 256, 0, stream>>>(zA, W + 144 * 64, b + 64, cnt, Se, ybuf, zB);
  k_gather<<<GTB, 256, 0, stream>>>(ybuf, zB, cnt, col_src, gamma + 64, beta + 64,
                                    emb + NG * HH);
  // layer 2: zB -> zA
  k_gemm<<<GB, 256, 0, stream>>>(zB, W + 2 * 144 * 64, b + 128, cnt, Se, ybuf, zA);
  k_gather<<<GTB, 256, 0, stream>>>(ybuf, zA, cnt, col_src, gamma + 128, beta + 128,
                                    emb + 2 * NG * HH);

  k_final<<<NG, 256, 0, stream>>>(zA, emb, nbr, fc1w, fc1b, fc2w, fc2b, out);
}

// Round 2
// 537.821 us; speedup vs baseline: 1.0345x; 1.0345x over previous
//
#include <hip/hip_runtime.h>
#include <hip/hip_bf16.h>

#define NN 100000   // nodes
#define NE 1600000  // edges
#define NG 100      // graphs
#define NPG 1000    // nodes per graph
#define CE 16       // edge channels
#define HH 64       // hidden
#define CAP 64      // max in-degree capacity (Poisson(16) tail ~3e-15 at 64)
#define BN_SCALE 0.99999500003749959f  // 1/sqrt(1+1e-5)

// ---------------- CSR fill: one int2 {src, eid} per edge slot ----------------
__global__ void k_fill(const int* __restrict__ ei, int* __restrict__ cnt,
                       int2* __restrict__ col) {
  int e = blockIdx.x * blockDim.x + threadIdx.x;
  if (e >= NE) return;
  int s = ei[e];        // edge_index[0][e] = src
  int d = ei[NE + e];   // edge_index[1][e] = dst
  int pos = atomicAdd(&cnt[d], 1);
  if (pos < CAP) col[(size_t)d * CAP + pos] = make_int2(s, e);
}

// ---------------- S_e[n][c] = 1 + sum_{e: dst=n} edge_attr[e][c] ----------------
__global__ void k_se(const int* __restrict__ cnt, const int2* __restrict__ col,
                     const float* __restrict__ ea, float* __restrict__ Se) {
  int t = blockIdx.x * blockDim.x + threadIdx.x;
  int n = t >> 4;
  if (n >= NN) return;
  int c = t & 15;
  int deg = min(cnt[n], CAP);
  const int2* cl = col + (size_t)n * CAP;
  float acc = 1.0f;  // self-loop ea = ones
  for (int k = 0; k < deg; ++k) {
    int e = cl[k].y;
    acc += ea[(size_t)e * CE + c];
  }
  Se[(size_t)n * CE + c] = acc;
}

// ---------------- per-layer node GEMM ----------------
// y[n][h] = x[n] @ W_j[:,h]  (bf16; message term, gathered later)
// z[n][h] = deg[n]*(x[n] @ W_i[:,h] + b[h]) + S_e[n] @ W_e[:,h]
__global__ __launch_bounds__(256) void k_gemm(
    const float* __restrict__ x, const float* __restrict__ W,
    const float* __restrict__ b, const int* __restrict__ cnt,
    const float* __restrict__ Se, __hip_bfloat16* __restrict__ y,
    float* __restrict__ z) {
  __shared__ float Wl[144 * 64];
  __shared__ float bl[64];
  for (int i = threadIdx.x; i < 144 * 64; i += blockDim.x) Wl[i] = W[i];
  if (threadIdx.x < 64) bl[threadIdx.x] = b[threadIdx.x];
  __syncthreads();
  int lane = threadIdx.x & 63;
  float wi[64], wj[64], we[16];
#pragma unroll
  for (int k = 0; k < 64; ++k) wi[k] = Wl[k * 64 + lane];
#pragma unroll
  for (int k = 0; k < 64; ++k) wj[k] = Wl[(64 + k) * 64 + lane];
#pragma unroll
  for (int k = 0; k < 16; ++k) we[k] = Wl[(128 + k) * 64 + lane];
  float bv = bl[lane];
  int wid = blockIdx.x * (blockDim.x >> 6) + (threadIdx.x >> 6);
  int nw = gridDim.x * (blockDim.x >> 6);
  for (int n0 = wid; n0 < NN; n0 += nw) {
    int n = __builtin_amdgcn_readfirstlane(n0);  // wave-uniform -> s_load x row
    const float* xr = x + (size_t)n * HH;
    const float* sr = Se + (size_t)n * CE;
    float a0 = 0.f, a1 = 0.f, a2 = 0.f, a3 = 0.f;
    float c0 = 0.f, c1 = 0.f, c2 = 0.f, c3 = 0.f;
#pragma unroll
    for (int k = 0; k < 64; k += 4) {
      float x0 = xr[k], x1 = xr[k + 1], x2 = xr[k + 2], x3 = xr[k + 3];
      a0 = fmaf(x0, wj[k], a0);
      a1 = fmaf(x1, wj[k + 1], a1);
      a2 = fmaf(x2, wj[k + 2], a2);
      a3 = fmaf(x3, wj[k + 3], a3);
      c0 = fmaf(x0, wi[k], c0);
      c1 = fmaf(x1, wi[k + 1], c1);
      c2 = fmaf(x2, wi[k + 2], c2);
      c3 = fmaf(x3, wi[k + 3], c3);
    }
    float s0 = 0.f, s1 = 0.f;
#pragma unroll
    for (int k = 0; k < 16; k += 2) {
      s0 = fmaf(sr[k], we[k], s0);
      s1 = fmaf(sr[k + 1], we[k + 1], s1);
    }
    float deg = (float)(min(cnt[n], CAP) + 1);
    y[(size_t)n * HH + lane] = __float2bfloat16((a0 + a1) + (a2 + a3));
    z[(size_t)n * HH + lane] = deg * (((c0 + c1) + (c2 + c3)) + bv) + (s0 + s1);
  }
}

// ---------------- per-layer gather + activation/BN ----------------
// x_new[n] = relu(bn(relu(z[n] + y[n] + sum_{e:dst=n} y[src_e])))  (in-place into z)
// XCD-chunked swizzle: each XCD owns a contiguous node range -> graph y-slabs
// (128 KB bf16) stay resident in that XCD's 4 MB L2 with ~16x reuse.
#define GTB 25000  // blocks; 4 waves/block, wave-per-node; 25000 = 8 * 3125
__global__ __launch_bounds__(256) void k_gather(
    const __hip_bfloat16* __restrict__ y, float* __restrict__ zx,
    const int* __restrict__ cnt, const int2* __restrict__ col,
    const float* __restrict__ gamma, const float* __restrict__ beta,
    float* __restrict__ emb) {
  int lane = threadIdx.x & 63;
  int orig = blockIdx.x;
  int blk = (orig & 7) * (GTB / 8) + (orig >> 3);  // XCD-contiguous mapping
  int n0 = blk * (blockDim.x >> 6) + (threadIdx.x >> 6);
  if (n0 >= NN) return;
  int n = __builtin_amdgcn_readfirstlane(n0);
  int deg = min(cnt[n], CAP);
  const int2* cl = col + (size_t)n * CAP;  // wave-uniform -> scalar loads
  float acc = zx[(size_t)n * HH + lane] +
              __bfloat162float(y[(size_t)n * HH + lane]);  // local + self-loop
  int k = 0;
  for (; k + 4 <= deg; k += 4) {
    int s0 = cl[k].x, s1 = cl[k + 1].x, s2 = cl[k + 2].x, s3 = cl[k + 3].x;
    float v0 = __bfloat162float(y[(size_t)s0 * HH + lane]);
    float v1 = __bfloat162float(y[(size_t)s1 * HH + lane]);
    float v2 = __bfloat162float(y[(size_t)s2 * HH + lane]);
    float v3 = __bfloat162float(y[(size_t)s3 * HH + lane]);
    acc += v0; acc += v1; acc += v2; acc += v3;
  }
  for (; k < deg; ++k) acc += __bfloat162float(y[(size_t)cl[k].x * HH + lane]);
  acc = fmaxf(acc, 0.f);                            // relu inside MP layer
  acc = gamma[lane] * acc * BN_SCALE + beta[lane];  // eval BN
  acc = fmaxf(acc, 0.f);                            // relu after BN
  zx[(size_t)n * HH + lane] = acc;
  if (n % NPG == 0) emb[(n / NPG) * HH + lane] = acc;  // spec_idx = g*NPG
}

// ---------------- readout: pool + MLP ----------------
__global__ __launch_bounds__(256) void k_final(
    const float* __restrict__ xf, const float* __restrict__ emb,
    const float* __restrict__ nbr, const float* __restrict__ fc1w,
    const float* __restrict__ fc1b, const float* __restrict__ fc2w,
    const float* __restrict__ fc2b, float* __restrict__ out) {
  __shared__ float feats[320];
  __shared__ float pool4[4][64];
  __shared__ float r1[256];
  int g = blockIdx.x;
  int t = threadIdx.x;
  int lane = t & 63, w = t >> 6;
  if (t >= 64) {  // fill embs: feats[64..255]
    int j = t - 64;
    feats[64 + j] = emb[((size_t)(j >> 6) * NG + g) * HH + (j & 63)];
  }
  if (t < 64) feats[256 + t] = nbr[(size_t)g * HH + t];  // neighbor
  float acc = 0.f;
  for (int i = w; i < NPG; i += 4) acc += xf[(size_t)(g * NPG + i) * HH + lane];
  pool4[w][lane] = acc;
  __syncthreads();
  if (t < 64) feats[t] = pool4[0][t] + pool4[1][t] + pool4[2][t] + pool4[3][t];
  __syncthreads();
  float a = fc1b[t];
  for (int k = 0; k < 320; ++k) a = fmaf(feats[k], fc1w[k * 256 + t], a);
  r1[t] = fmaxf(a, 0.f);
  __syncthreads();
  if (t < 4) {
    float o = fc2b[t];
    for (int k = 0; k < 256; ++k) o = fmaf(r1[k], fc2w[k * 4 + t], o);
    out[g * 4 + t] = o;
  }
}

extern "C" void kernel_launch(void* const* d_in, const int* in_sizes, int n_in,
                              void* d_out, int out_size, void* d_ws, size_t ws_size,
                              hipStream_t stream) {
  const float* x     = (const float*)d_in[0];
  const float* eattr = (const float*)d_in[1];
  const float* nbr   = (const float*)d_in[2];
  const float* W     = (const float*)d_in[3];
  const float* b     = (const float*)d_in[4];
  const float* gamma = (const float*)d_in[5];
  const float* beta  = (const float*)d_in[6];
  const float* fc1w  = (const float*)d_in[7];
  const float* fc1b  = (const float*)d_in[8];
  const float* fc2w  = (const float*)d_in[9];
  const float* fc2b  = (const float*)d_in[10];
  const int*   ei    = (const int*)d_in[11];
  float* out = (float*)d_out;
  (void)in_sizes; (void)n_in; (void)out_size; (void)ws_size;

  char* p = (char*)d_ws;
  size_t off = 0;
  auto alloc = [&](size_t bytes) {
    char* q = p + off;
    off += (bytes + 255) & ~(size_t)255;
    return q;
  };
  int*            cnt = (int*)alloc((size_t)NN * 4);
  int2*           col = (int2*)alloc((size_t)NN * CAP * 8);
  float*          Se  = (float*)alloc((size_t)NN * CE * 4);
  __hip_bfloat16* ybuf = (__hip_bfloat16*)alloc((size_t)NN * HH * 2);
  float*          zA  = (float*)alloc((size_t)NN * HH * 4);
  float*          zB  = (float*)alloc((size_t)NN * HH * 4);
  float*          emb = (float*)alloc((size_t)3 * NG * HH * 4);

  hipMemsetAsync(cnt, 0, (size_t)NN * 4, stream);
  k_fill<<<(NE + 255) / 256, 256, 0, stream>>>(ei, cnt, col);
  k_se<<<(NN * 16 + 255) / 256, 256, 0, stream>>>(cnt, col, eattr, Se);

  const int GB = 768;  // gemm: 3072 waves, grid-stride over nodes

  // layer 0: x -> zA
  k_gemm<<<GB, 256, 0, stream>>>(x, W, b, cnt, Se, ybuf, zA);
  k_gather<<<GTB, 256, 0, stream>>>(ybuf, zA, cnt, col, gamma, beta, emb);
  // layer 1: zA -> zB
  k_gemm<<<GB, 256, 0, stream>>>(zA, W + 144 * 64, b + 64, cnt, Se, ybuf, zB);
  k_gather<<<GTB, 256, 0, stream>>>(ybuf, zB, cnt, col, gamma + 64, beta + 64,
                                    emb + NG * HH);
  // layer 2: zB -> zA
  k_gemm<<<GB, 256, 0, stream>>>(zB, W + 2 * 144 * 64, b + 128, cnt, Se, ybuf, zA);
  k_gather<<<GTB, 256, 0, stream>>>(ybuf, zA, cnt, col, gamma + 128, beta + 128,
                                    emb + 2 * NG * HH);

  k_final<<<NG, 256, 0, stream>>>(zA, emb, nbr, fc1w, fc1b, fc2w, fc2b, out);
}

// Round 3
// 471.621 us; speedup vs baseline: 1.1797x; 1.1404x over previous
//
#include <hip/hip_runtime.h>
#include <hip/hip_bf16.h>

#define NN 100000   // nodes
#define NE 1600000  // edges
#define NG 100      // graphs
#define NPG 1000    // nodes per graph
#define CE 16       // edge channels
#define HH 64       // hidden
#define CAP 64      // max in-degree capacity (Poisson(16) tail ~3e-15 at 64)
#define BN_SCALE 0.99999500003749959f  // 1/sqrt(1+1e-5)
#define NXCD 8
#define NRANGE (NN / NXCD)  // 12500 nodes per XCD range

// ---------------- CSR fill, XCD-local by dst-range ----------------
// Each edge-chunk is visited by 8 blocks (one per XCD via blockIdx&7); each
// block keeps only dst in its own 12500-node range -> cnt/col atomics+stores
// stay in that XCD's L2 (no cross-XCD line ping-pong). The 8x chunk re-read
// is served by the shared 256MB L3. Correct for ANY block->XCD mapping.
#define FCHUNK 8000  // edges per chunk; NE/FCHUNK = 200 chunks, grid = 1600
__global__ __launch_bounds__(256) void k_fill(const int* __restrict__ ei,
                                              int* __restrict__ cnt,
                                              int2* __restrict__ col) {
  int xcd = blockIdx.x & 7;
  int chunk = blockIdx.x >> 3;
  int lo = xcd * NRANGE, hi = lo + NRANGE;
  int e0 = chunk * FCHUNK;
  for (int i = threadIdx.x; i < FCHUNK; i += 256) {
    int e = e0 + i;
    int d = ei[NE + e];  // dst (coalesced)
    int s = ei[e];       // src (coalesced)
    if (d >= lo && d < hi) {
      int pos = atomicAdd(&cnt[d], 1);
      if (pos < CAP) col[(size_t)d * CAP + pos] = make_int2(s, e);
    }
  }
}

// ---------------- S_e[n][c] = 1 + sum_{e: dst=n} edge_attr[e][c] ----------------
// 16 nodes/block; XCD-swizzled so col/cnt reads hit the L2 that k_fill dirtied.
#define SEB 6256  // 8 * 782 blocks (>= NN/16 = 6250)
__global__ __launch_bounds__(256) void k_se(const int* __restrict__ cnt,
                                            const int2* __restrict__ col,
                                            const float* __restrict__ ea,
                                            float* __restrict__ Se) {
  int blk = (blockIdx.x & 7) * (SEB / 8) + (blockIdx.x >> 3);
  int t = blk * 256 + threadIdx.x;
  int n = t >> 4;
  if (n >= NN) return;
  int c = t & 15;
  int deg = min(cnt[n], CAP);
  const int2* cl = col + (size_t)n * CAP;
  float acc = 1.0f;  // self-loop ea = ones
  for (int k = 0; k < deg; ++k) {
    int e = cl[k].y;
    acc += ea[(size_t)e * CE + c];
  }
  Se[(size_t)n * CE + c] = acc;
}

// ---------------- per-layer node GEMM ----------------
// y[n][h] = x[n] @ W_j[:,h]  (bf16; message term, gathered later)
// z[n][h] = deg[n]*(x[n] @ W_i[:,h] + b[h]) + S_e[n] @ W_e[:,h]
// Per-XCD node-range stride: y/z writes land in the local L2 that k_gather
// (same node ranges) will read.
#define GB 768  // 96 blocks per XCD group -> 384 waves per 12500-node range
__global__ __launch_bounds__(256) void k_gemm(
    const float* __restrict__ x, const float* __restrict__ W,
    const float* __restrict__ b, const int* __restrict__ cnt,
    const float* __restrict__ Se, __hip_bfloat16* __restrict__ y,
    float* __restrict__ z) {
  __shared__ float Wl[144 * 64];
  __shared__ float bl[64];
  for (int i = threadIdx.x; i < 144 * 64; i += blockDim.x) Wl[i] = W[i];
  if (threadIdx.x < 64) bl[threadIdx.x] = b[threadIdx.x];
  __syncthreads();
  int lane = threadIdx.x & 63;
  float wi[64], wj[64], we[16];
#pragma unroll
  for (int k = 0; k < 64; ++k) wi[k] = Wl[k * 64 + lane];
#pragma unroll
  for (int k = 0; k < 64; ++k) wj[k] = Wl[(64 + k) * 64 + lane];
#pragma unroll
  for (int k = 0; k < 16; ++k) we[k] = Wl[(128 + k) * 64 + lane];
  float bv = bl[lane];
  int xcd = blockIdx.x & 7;
  int wid = (blockIdx.x >> 3) * 4 + (threadIdx.x >> 6);  // 0..383 within range
  int lo = xcd * NRANGE, hi = lo + NRANGE;
  const int stride = (GB / 8) * 4;
  for (int n0 = lo + wid; n0 < hi; n0 += stride) {
    int n = __builtin_amdgcn_readfirstlane(n0);  // wave-uniform -> s_load x row
    const float* xr = x + (size_t)n * HH;
    const float* sr = Se + (size_t)n * CE;
    float a0 = 0.f, a1 = 0.f, a2 = 0.f, a3 = 0.f;
    float c0 = 0.f, c1 = 0.f, c2 = 0.f, c3 = 0.f;
#pragma unroll
    for (int k = 0; k < 64; k += 4) {
      float x0 = xr[k], x1 = xr[k + 1], x2 = xr[k + 2], x3 = xr[k + 3];
      a0 = fmaf(x0, wj[k], a0);
      a1 = fmaf(x1, wj[k + 1], a1);
      a2 = fmaf(x2, wj[k + 2], a2);
      a3 = fmaf(x3, wj[k + 3], a3);
      c0 = fmaf(x0, wi[k], c0);
      c1 = fmaf(x1, wi[k + 1], c1);
      c2 = fmaf(x2, wi[k + 2], c2);
      c3 = fmaf(x3, wi[k + 3], c3);
    }
    float s0 = 0.f, s1 = 0.f;
#pragma unroll
    for (int k = 0; k < 16; k += 2) {
      s0 = fmaf(sr[k], we[k], s0);
      s1 = fmaf(sr[k + 1], we[k + 1], s1);
    }
    float deg = (float)(min(cnt[n], CAP) + 1);
    y[(size_t)n * HH + lane] = __float2bfloat16((a0 + a1) + (a2 + a3));
    z[(size_t)n * HH + lane] = deg * (((c0 + c1) + (c2 + c3)) + bv) + (s0 + s1);
  }
}

// ---------------- per-layer gather + activation/BN ----------------
// x_new[n] = relu(bn(relu(z[n] + y[n] + sum_{e:dst=n} y[src_e])))  (in-place into z)
// Node ranges match k_fill/k_gemm -> y rows, col, z all local-L2.
#define GTB 25000  // 4 waves/block, wave-per-node; 25000 = 8 * 3125
__global__ __launch_bounds__(256) void k_gather(
    const __hip_bfloat16* __restrict__ y, float* __restrict__ zx,
    const int* __restrict__ cnt, const int2* __restrict__ col,
    const float* __restrict__ gamma, const float* __restrict__ beta,
    float* __restrict__ emb) {
  int lane = threadIdx.x & 63;
  int orig = blockIdx.x;
  int blk = (orig & 7) * (GTB / 8) + (orig >> 3);  // XCD-contiguous mapping
  int n0 = blk * (blockDim.x >> 6) + (threadIdx.x >> 6);
  if (n0 >= NN) return;
  int n = __builtin_amdgcn_readfirstlane(n0);
  int deg = min(cnt[n], CAP);
  const int2* cl = col + (size_t)n * CAP;  // wave-uniform -> scalar loads
  float acc = zx[(size_t)n * HH + lane] +
              __bfloat162float(y[(size_t)n * HH + lane]);  // local + self-loop
  int k = 0;
  for (; k + 4 <= deg; k += 4) {
    int s0 = cl[k].x, s1 = cl[k + 1].x, s2 = cl[k + 2].x, s3 = cl[k + 3].x;
    float v0 = __bfloat162float(y[(size_t)s0 * HH + lane]);
    float v1 = __bfloat162float(y[(size_t)s1 * HH + lane]);
    float v2 = __bfloat162float(y[(size_t)s2 * HH + lane]);
    float v3 = __bfloat162float(y[(size_t)s3 * HH + lane]);
    acc += v0; acc += v1; acc += v2; acc += v3;
  }
  for (; k < deg; ++k) acc += __bfloat162float(y[(size_t)cl[k].x * HH + lane]);
  acc = fmaxf(acc, 0.f);                            // relu inside MP layer
  acc = gamma[lane] * acc * BN_SCALE + beta[lane];  // eval BN
  acc = fmaxf(acc, 0.f);                            // relu after BN
  zx[(size_t)n * HH + lane] = acc;
  if (n % NPG == 0) emb[(n / NPG) * HH + lane] = acc;  // spec_idx = g*NPG
}

// ---------------- readout: pool + MLP ----------------
__global__ __launch_bounds__(256) void k_final(
    const float* __restrict__ xf, const float* __restrict__ emb,
    const float* __restrict__ nbr, const float* __restrict__ fc1w,
    const float* __restrict__ fc1b, const float* __restrict__ fc2w,
    const float* __restrict__ fc2b, float* __restrict__ out) {
  __shared__ float feats[320];
  __shared__ float pool4[4][64];
  __shared__ float r1[256];
  int g = blockIdx.x;
  int t = threadIdx.x;
  int lane = t & 63, w = t >> 6;
  if (t >= 64) {  // fill embs: feats[64..255]
    int j = t - 64;
    feats[64 + j] = emb[((size_t)(j >> 6) * NG + g) * HH + (j & 63)];
  }
  if (t < 64) feats[256 + t] = nbr[(size_t)g * HH + t];  // neighbor
  float acc = 0.f;
  for (int i = w; i < NPG; i += 4) acc += xf[(size_t)(g * NPG + i) * HH + lane];
  pool4[w][lane] = acc;
  __syncthreads();
  if (t < 64) feats[t] = pool4[0][t] + pool4[1][t] + pool4[2][t] + pool4[3][t];
  __syncthreads();
  float a = fc1b[t];
  for (int k = 0; k < 320; ++k) a = fmaf(feats[k], fc1w[k * 256 + t], a);
  r1[t] = fmaxf(a, 0.f);
  __syncthreads();
  if (t < 4) {
    float o = fc2b[t];
    for (int k = 0; k < 256; ++k) o = fmaf(r1[k], fc2w[k * 4 + t], o);
    out[g * 4 + t] = o;
  }
}

extern "C" void kernel_launch(void* const* d_in, const int* in_sizes, int n_in,
                              void* d_out, int out_size, void* d_ws, size_t ws_size,
                              hipStream_t stream) {
  const float* x     = (const float*)d_in[0];
  const float* eattr = (const float*)d_in[1];
  const float* nbr   = (const float*)d_in[2];
  const float* W     = (const float*)d_in[3];
  const float* b     = (const float*)d_in[4];
  const float* gamma = (const float*)d_in[5];
  const float* beta  = (const float*)d_in[6];
  const float* fc1w  = (const float*)d_in[7];
  const float* fc1b  = (const float*)d_in[8];
  const float* fc2w  = (const float*)d_in[9];
  const float* fc2b  = (const float*)d_in[10];
  const int*   ei    = (const int*)d_in[11];
  float* out = (float*)d_out;
  (void)in_sizes; (void)n_in; (void)out_size; (void)ws_size;

  char* p = (char*)d_ws;
  size_t off = 0;
  auto alloc = [&](size_t bytes) {
    char* q = p + off;
    off += (bytes + 255) & ~(size_t)255;
    return q;
  };
  int*            cnt  = (int*)alloc((size_t)NN * 4);
  int2*           col  = (int2*)alloc((size_t)NN * CAP * 8);
  float*          Se   = (float*)alloc((size_t)NN * CE * 4);
  __hip_bfloat16* ybuf = (__hip_bfloat16*)alloc((size_t)NN * HH * 2);
  float*          zA   = (float*)alloc((size_t)NN * HH * 4);
  float*          zB   = (float*)alloc((size_t)NN * HH * 4);
  float*          emb  = (float*)alloc((size_t)3 * NG * HH * 4);

  hipMemsetAsync(cnt, 0, (size_t)NN * 4, stream);
  k_fill<<<(NE / FCHUNK) * 8, 256, 0, stream>>>(ei, cnt, col);
  k_se<<<SEB, 256, 0, stream>>>(cnt, col, eattr, Se);

  // layer 0: x -> zA
  k_gemm<<<GB, 256, 0, stream>>>(x, W, b, cnt, Se, ybuf, zA);
  k_gather<<<GTB, 256, 0, stream>>>(ybuf, zA, cnt, col, gamma, beta, emb);
  // layer 1: zA -> zB
  k_gemm<<<GB, 256, 0, stream>>>(zA, W + 144 * 64, b + 64, cnt, Se, ybuf, zB);
  k_gather<<<GTB, 256, 0, stream>>>(ybuf, zB, cnt, col, gamma + 64, beta + 64,
                                    emb + NG * HH);
  // layer 2: zB -> zA
  k_gemm<<<GB, 256, 0, stream>>>(zB, W + 2 * 144 * 64, b + 128, cnt, Se, ybuf, zA);
  k_gather<<<GTB, 256, 0, stream>>>(ybuf, zA, cnt, col, gamma + 128, beta + 128,
                                    emb + 2 * NG * HH);

  k_final<<<NG, 256, 0, stream>>>(zA, emb, nbr, fc1w, fc1b, fc2w, fc2b, out);
}